// Round 4
// baseline (358.960 us; speedup 1.0000x reference)
//
#include <hip/hip_runtime.h>
#include <hip/hip_bf16.h>
#include <cstdint>
#include <cstddef>

// B=4, T=256, U=64, H=512, K=512, V=1024; M = 65536 rows, log_softmax over V.
// Round 4: B (W2 image, 1 MB bf16) is L2-resident -> read fragments DIRECTLY
// from global into registers (no LDS staging, no K-loop barriers).
// Blocks: 32 rows x 1024 cols, 512 threads = 8 waves (1M x 8N), 2 blocks/CU.

typedef __attribute__((ext_vector_type(8))) short short8;
typedef __attribute__((ext_vector_type(4))) float f32x4;

#define AS_STRIDE 520                 // 512 + 8 bf16 pad: dword stride 260 = 4 mod 32
#define BS_CHUNK 65536                // one BK=32 chunk of W2 image: 1024 cols * 64 B

// ws layout
#define WS_EP_OFF 0                           // 1024*512 f32 = 2 MiB
#define WS_DP_OFF (1024 * 512 * 4)            // 256*512 f32 = 512 KiB
#define WS_W2_OFF (WS_DP_OFF + 256 * 512 * 4) // staged W2 bf16: 16 chunks * 64 KiB

__device__ __forceinline__ unsigned short f2bf(float x) {
  unsigned int u = __builtin_bit_cast(unsigned int, x);
  u += 0x7FFFu + ((u >> 16) & 1u);
  return (unsigned short)(u >> 16);
}

__device__ __forceinline__ float fast_tanh(float x) {
  float ax = fabsf(x);
  float e = __expf(-2.0f * ax);
  float t = (1.0f - e) / (1.0f + e);
  return copysignf(t, x);
}

// ---------------------------------------------------------------------------
// prep (fused): blocks 0..319 -> ep/dp projections (4 rows each);
//               blocks 320..351 -> W2 repack to bf16 staged image:
//   w2st[kc*65536 + v*64 + ki*2] = bf16(W2[kc*32+ki][v])
// ---------------------------------------------------------------------------
__global__ __launch_bounds__(512) void prep(
    const float* __restrict__ enc, const float* __restrict__ dec,
    const float* __restrict__ W1, const float* __restrict__ b1,
    const float* __restrict__ W2,
    float* __restrict__ ep, float* __restrict__ dp, char* __restrict__ w2st) {
  __shared__ float As[4 * 512];
  const int tid = threadIdx.x;
  if (blockIdx.x < 320) {
    const int r0 = blockIdx.x * 4;
    const bool isenc = (r0 < 1024);
    const float* A = isenc ? (enc + (size_t)r0 * 512) : (dec + (size_t)(r0 - 1024) * 512);
    const float* W = isenc ? W1 : (W1 + 512 * 512);
    float* O = isenc ? (ep + (size_t)r0 * 512) : (dp + (size_t)(r0 - 1024) * 512);

    for (int idx = tid; idx < 4 * 512; idx += 512) As[idx] = A[idx];
    __syncthreads();

    const int c = tid;
    float acc[4] = {0.f, 0.f, 0.f, 0.f};
    const float4* As4 = (const float4*)As;
#pragma unroll 4
    for (int k4 = 0; k4 < 128; ++k4) {
      const int kb = k4 * 4;
      float w0 = W[(size_t)(kb + 0) * 512 + c];
      float w1 = W[(size_t)(kb + 1) * 512 + c];
      float w2 = W[(size_t)(kb + 2) * 512 + c];
      float w3 = W[(size_t)(kb + 3) * 512 + c];
#pragma unroll
      for (int r = 0; r < 4; ++r) {
        float4 a = As4[r * 128 + k4];
        acc[r] += a.x * w0 + a.y * w1 + a.z * w2 + a.w * w3;
      }
    }
    const float bias = isenc ? b1[c] : 0.0f;
#pragma unroll
    for (int r = 0; r < 4; ++r) O[(size_t)r * 512 + c] = acc[r] + bias;
  } else {
    const int g = (blockIdx.x - 320) * 512 + tid;  // 0..16383
    const int v = g & 1023;
    const int kc = g >> 10;
    unsigned short vals[32];
#pragma unroll
    for (int ki = 0; ki < 32; ++ki)
      vals[ki] = f2bf(W2[(size_t)(kc * 32 + ki) * 1024 + v]);
    uint4* dst = (uint4*)(w2st + (size_t)kc * BS_CHUNK + (size_t)v * 64);
    const uint4* s = (const uint4*)vals;
    dst[0] = s[0]; dst[1] = s[1]; dst[2] = s[2]; dst[3] = s[3];
  }
}

// ---------------------------------------------------------------------------
// joint: block = 32 rows x V=1024; 512 threads = 8 waves, wave w owns cols
// [w*128, w*128+128). B frags from global (L2) with 1-step register prefetch;
// A (tanh tile) in LDS; NO barriers in the K-loop.
// ---------------------------------------------------------------------------
__global__ __launch_bounds__(512, 4) void joint(
    const float* __restrict__ ep, const float* __restrict__ dp,
    const char* __restrict__ w2st, const float* __restrict__ b2,
    float* __restrict__ out) {
  __shared__ unsigned short As[32 * AS_STRIDE];   // 33280 B
  __shared__ float redM[8 * 32];
  __shared__ float redS[8 * 32];

  const int tid = threadIdx.x;
  const int wave = tid >> 6, lane = tid & 63;
  const int lo = lane & 15, hi = lane >> 4;
  const int m0 = blockIdx.x * 32;
  const int bt = m0 >> 6;                    // b*256 + t
  const int dprow0 = ((bt >> 8) << 6) + (m0 & 63);  // b*64 + u0
  const int nbase = wave * 128;

  // per-lane byte offset of frag (ni=0) within one K-chunk of the W2 image
  const char* bbase = w2st + (size_t)(nbase + lo) * 64 + hi * 16;

  // -- prologue: issue kc=0 B-frag loads (latency hides under tanh) --
  short8 b[8];
#pragma unroll
  for (int ni = 0; ni < 8; ++ni)
    b[ni] = *(const short8*)(bbase + ni * 1024);

  // -- phase 1: A-tile hidden[32][512] = tanh(ep + dp) -> bf16 LDS --
  {
    const int c = tid;  // 0..511
    const float e = ep[(size_t)bt * 512 + c];
#pragma unroll 4
    for (int r = 0; r < 32; ++r) {
      float h = fast_tanh(e + dp[(size_t)(dprow0 + r) * 512 + c]);
      As[r * AS_STRIDE + c] = f2bf(h);
    }
  }

  f32x4 acc[2][8];
#pragma unroll
  for (int mi = 0; mi < 2; ++mi)
#pragma unroll
    for (int ni = 0; ni < 8; ++ni)
#pragma unroll
      for (int j = 0; j < 4; ++j) acc[mi][ni][j] = 0.0f;

  __syncthreads();  // A visible; only barrier before epilogue

  // -- K loop: 16 chunks of BK=32, barrier-free, 1-deep B prefetch --
#pragma unroll
  for (int kc = 0; kc < 16; ++kc) {
    short8 bn[8];
    if (kc < 15) {
      const char* src = bbase + (size_t)(kc + 1) * BS_CHUNK;
#pragma unroll
      for (int ni = 0; ni < 8; ++ni)
        bn[ni] = *(const short8*)(src + ni * 1024);
    }
    short8 a0 = *(const short8*)(As + (size_t)lo * AS_STRIDE + kc * 32 + hi * 8);
    short8 a1 = *(const short8*)(As + (size_t)(16 + lo) * AS_STRIDE + kc * 32 + hi * 8);
    __builtin_amdgcn_s_setprio(1);
#pragma unroll
    for (int ni = 0; ni < 8; ++ni) {
      acc[0][ni] = __builtin_amdgcn_mfma_f32_16x16x32_bf16(a0, b[ni], acc[0][ni], 0, 0, 0);
      acc[1][ni] = __builtin_amdgcn_mfma_f32_16x16x32_bf16(a1, b[ni], acc[1][ni], 0, 0, 0);
    }
    __builtin_amdgcn_s_setprio(0);
    if (kc < 15) {
#pragma unroll
      for (int ni = 0; ni < 8; ++ni) b[ni] = bn[ni];
    }
  }

  // -- phase 3: +b2, log_softmax over V, store --
  float b2v[8];
#pragma unroll
  for (int ni = 0; ni < 8; ++ni) b2v[ni] = b2[nbase + ni * 16 + lo];
#pragma unroll
  for (int mi = 0; mi < 2; ++mi)
#pragma unroll
    for (int ni = 0; ni < 8; ++ni)
#pragma unroll
      for (int j = 0; j < 4; ++j) acc[mi][ni][j] += b2v[ni];

  float pm[2][4];
#pragma unroll
  for (int mi = 0; mi < 2; ++mi)
#pragma unroll
    for (int r = 0; r < 4; ++r) {
      float m = -3.402823e38f;
#pragma unroll
      for (int ni = 0; ni < 8; ++ni) m = fmaxf(m, acc[mi][ni][r]);
      pm[mi][r] = m;
    }
#pragma unroll
  for (int off = 1; off < 16; off <<= 1)
#pragma unroll
    for (int mi = 0; mi < 2; ++mi)
#pragma unroll
      for (int r = 0; r < 4; ++r)
        pm[mi][r] = fmaxf(pm[mi][r], __shfl_xor(pm[mi][r], off));
  if (lo == 0) {
#pragma unroll
    for (int mi = 0; mi < 2; ++mi)
#pragma unroll
      for (int r = 0; r < 4; ++r)
        redM[wave * 32 + mi * 16 + hi * 4 + r] = pm[mi][r];
  }
  __syncthreads();
  float rm[2][4];
#pragma unroll
  for (int mi = 0; mi < 2; ++mi)
#pragma unroll
    for (int r = 0; r < 4; ++r) {
      const int row = mi * 16 + hi * 4 + r;
      float m = redM[row];
#pragma unroll
      for (int w = 1; w < 8; ++w) m = fmaxf(m, redM[w * 32 + row]);
      rm[mi][r] = m;
    }

  float ps[2][4];
#pragma unroll
  for (int mi = 0; mi < 2; ++mi)
#pragma unroll
    for (int r = 0; r < 4; ++r) {
      float s = 0.0f;
#pragma unroll
      for (int ni = 0; ni < 8; ++ni) s += __expf(acc[mi][ni][r] - rm[mi][r]);
      ps[mi][r] = s;
    }
#pragma unroll
  for (int off = 1; off < 16; off <<= 1)
#pragma unroll
    for (int mi = 0; mi < 2; ++mi)
#pragma unroll
      for (int r = 0; r < 4; ++r)
        ps[mi][r] += __shfl_xor(ps[mi][r], off);
  if (lo == 0) {
#pragma unroll
    for (int mi = 0; mi < 2; ++mi)
#pragma unroll
      for (int r = 0; r < 4; ++r)
        redS[wave * 32 + mi * 16 + hi * 4 + r] = ps[mi][r];
  }
  __syncthreads();

#pragma unroll
  for (int mi = 0; mi < 2; ++mi)
#pragma unroll
    for (int r = 0; r < 4; ++r) {
      const int row = mi * 16 + hi * 4 + r;
      float s = 0.0f;
#pragma unroll
      for (int w = 0; w < 8; ++w) s += redS[w * 32 + row];
      const float sub = rm[mi][r] + __logf(s);
      float* op = out + (size_t)(m0 + row) * 1024 + nbase + lo;
#pragma unroll
      for (int ni = 0; ni < 8; ++ni) op[ni * 16] = acc[mi][ni][r] - sub;
    }
}

// ---------------------------------------------------------------------------
extern "C" void kernel_launch(void* const* d_in, const int* in_sizes, int n_in,
                              void* d_out, int out_size, void* d_ws, size_t ws_size,
                              hipStream_t stream) {
  const float* enc = (const float*)d_in[0];
  const float* dec = (const float*)d_in[1];
  const float* W1  = (const float*)d_in[2];
  const float* b1  = (const float*)d_in[3];
  const float* W2  = (const float*)d_in[4];
  const float* b2  = (const float*)d_in[5];
  float* out = (float*)d_out;

  char* ws = (char*)d_ws;
  float* ep = (float*)(ws + WS_EP_OFF);
  float* dp = (float*)(ws + WS_DP_OFF);
  char* w2st = ws + WS_W2_OFF;

  prep<<<352, 512, 0, stream>>>(enc, dec, W1, b1, W2, ep, dp, w2st);
  joint<<<2048, 512, 0, stream>>>(ep, dp, w2st, b2, out);
}

// Round 5
// 180.506 us; speedup vs baseline: 1.9886x; 1.9886x over previous
//
#include <hip/hip_runtime.h>
#include <hip/hip_bf16.h>
#include <cstdint>
#include <cstddef>

// B=4, T=256, U=64, H=512, K=512, V=1024; M = 65536 rows, log_softmax over V.
// Round 5: BM=64 (one (b,t) per block), 512 threads = 8 waves (1Mx8N).
// B read DIRECTLY from L2-resident w2st image into regs (1-deep prefetch,
// zero barriers in K-loop). A (tanh tile) in LDS, XOR-swizzled. No spills:
// launch_bounds(512,2) -> 256 VGPR cap, K-loop not unrolled.

typedef __attribute__((ext_vector_type(8))) short short8;
typedef __attribute__((ext_vector_type(4))) float f32x4;

#define BS_CHUNK 65536                // one BK=32 chunk of W2 image: 1024 cols * 64 B

// ws layout
#define WS_EP_OFF 0                           // 1024*512 f32 = 2 MiB
#define WS_DP_OFF (1024 * 512 * 4)            // 256*512 f32 = 512 KiB
#define WS_W2_OFF (WS_DP_OFF + 256 * 512 * 4) // W2 bf16 image: 16 chunks * 64 KiB

#define SMEM_RED_OFF 65536                    // A tile: 64 rows * 1024 B
#define SMEM_TOTAL (65536 + 4096)             // + redM[8][64], redS[8][64]

__device__ __forceinline__ unsigned short f2bf(float x) {
  unsigned int u = __builtin_bit_cast(unsigned int, x);
  u += 0x7FFFu + ((u >> 16) & 1u);
  return (unsigned short)(u >> 16);
}

__device__ __forceinline__ float fast_tanh(float x) {
  float ax = fabsf(x);
  float e = __expf(-2.0f * ax);
  float t = (1.0f - e) / (1.0f + e);
  return copysignf(t, x);
}

// ---------------------------------------------------------------------------
// prep (fused): blocks 0..319 -> ep/dp projections (4 rows each);
//               blocks 320..351 -> W2 repack to bf16 image:
//   w2st[kc*65536 + v*64 + ki*2] = bf16(W2[kc*32+ki][v])
// ---------------------------------------------------------------------------
__global__ __launch_bounds__(512) void prep(
    const float* __restrict__ enc, const float* __restrict__ dec,
    const float* __restrict__ W1, const float* __restrict__ b1,
    const float* __restrict__ W2,
    float* __restrict__ ep, float* __restrict__ dp, char* __restrict__ w2st) {
  __shared__ float As[4 * 512];
  const int tid = threadIdx.x;
  if (blockIdx.x < 320) {
    const int r0 = blockIdx.x * 4;
    const bool isenc = (r0 < 1024);
    const float* A = isenc ? (enc + (size_t)r0 * 512) : (dec + (size_t)(r0 - 1024) * 512);
    const float* W = isenc ? W1 : (W1 + 512 * 512);
    float* O = isenc ? (ep + (size_t)r0 * 512) : (dp + (size_t)(r0 - 1024) * 512);

    for (int idx = tid; idx < 4 * 512; idx += 512) As[idx] = A[idx];
    __syncthreads();

    const int c = tid;
    float acc[4] = {0.f, 0.f, 0.f, 0.f};
    const float4* As4 = (const float4*)As;
#pragma unroll 4
    for (int k4 = 0; k4 < 128; ++k4) {
      const int kb = k4 * 4;
      float w0 = W[(size_t)(kb + 0) * 512 + c];
      float w1 = W[(size_t)(kb + 1) * 512 + c];
      float w2 = W[(size_t)(kb + 2) * 512 + c];
      float w3 = W[(size_t)(kb + 3) * 512 + c];
#pragma unroll
      for (int r = 0; r < 4; ++r) {
        float4 a = As4[r * 128 + k4];
        acc[r] += a.x * w0 + a.y * w1 + a.z * w2 + a.w * w3;
      }
    }
    const float bias = isenc ? b1[c] : 0.0f;
#pragma unroll
    for (int r = 0; r < 4; ++r) O[(size_t)r * 512 + c] = acc[r] + bias;
  } else {
    const int g = (blockIdx.x - 320) * 512 + tid;  // 0..16383
    const int v = g & 1023;
    const int kc = g >> 10;
    unsigned short vals[32];
#pragma unroll
    for (int ki = 0; ki < 32; ++ki)
      vals[ki] = f2bf(W2[(size_t)(kc * 32 + ki) * 1024 + v]);
    uint4* dst = (uint4*)(w2st + (size_t)kc * BS_CHUNK + (size_t)v * 64);
    const uint4* s = (const uint4*)vals;
    dst[0] = s[0]; dst[1] = s[1]; dst[2] = s[2]; dst[3] = s[3];
  }
}

// ---------------------------------------------------------------------------
// joint: block = 64 rows (one (b,t), all u) x V=1024; 512 threads = 8 waves.
// Wave w: rows 0..63 (4 m-frags), cols [w*128, w*128+128) (8 n-frags).
// ---------------------------------------------------------------------------
__global__ __launch_bounds__(512, 2) void joint(
    const float* __restrict__ ep, const float* __restrict__ dp,
    const char* __restrict__ w2st, const float* __restrict__ b2,
    float* __restrict__ out) {
  extern __shared__ char smem[];
  char* As = smem;                            // [64 rows][1024 B], XOR-swizzled
  float* redM = (float*)(smem + SMEM_RED_OFF);  // [8][64]
  float* redS = redM + 512;

  const int tid = threadIdx.x;
  const int wave = tid >> 6, lane = tid & 63;
  const int lo = lane & 15, hi = lane >> 4;
  const int bt = blockIdx.x;                 // one (b,t)
  const int m0 = bt * 64;
  const int dprow0 = (bt >> 8) * 64;         // b*64
  const int nbase = wave * 128;

  // per-lane base into one K-chunk of the W2 image (frag ni adds ni*1024)
  const char* bbase = w2st + (size_t)(nbase + lo) * 64 + hi * 16;

  // -- prologue: issue chunk-0 B loads (latency hides under tanh phase) --
  short8 b[8];
#pragma unroll
  for (int ni = 0; ni < 8; ++ni) b[ni] = *(const short8*)(bbase + ni * 1024);

  // -- phase 1: A[64][512] = tanh(ep+dp) -> bf16 LDS, swizzle addr^((row&7)<<4)
  {
    const int c0 = (tid & 63) * 8;
    const int rb = tid >> 6;                 // wave index: rows rb, rb+8, ..., rb+56
    const float* epr = ep + (size_t)bt * 512 + c0;
    float e0[8];
    *(float4*)(e0) = *(const float4*)(epr);
    *(float4*)(e0 + 4) = *(const float4*)(epr + 4);
#pragma unroll
    for (int p = 0; p < 8; ++p) {
      const int row = rb + p * 8;
      const float* dpr = dp + (size_t)(dprow0 + row) * 512 + c0;
      float d0[8];
      *(float4*)(d0) = *(const float4*)(dpr);
      *(float4*)(d0 + 4) = *(const float4*)(dpr + 4);
      unsigned short h[8];
#pragma unroll
      for (int j = 0; j < 8; ++j) h[j] = f2bf(fast_tanh(e0[j] + d0[j]));
      *(uint4*)(As + ((row * 1024 + c0 * 2) ^ ((row & 7) << 4))) = *(const uint4*)h;
    }
  }

  f32x4 acc[4][8];
#pragma unroll
  for (int mi = 0; mi < 4; ++mi)
#pragma unroll
    for (int ni = 0; ni < 8; ++ni)
#pragma unroll
      for (int j = 0; j < 4; ++j) acc[mi][ni][j] = 0.0f;

  __syncthreads();  // A visible; the only barrier before the epilogue

  const int axor = (lo & 7) << 4;

  // -- K loop: 16 chunks of BK=32, barrier-free, 1-deep B prefetch --
  for (int kc = 0; kc < 16; ++kc) {
    short8 bn[8];
    if (kc < 15) {
      const char* src = bbase + (size_t)(kc + 1) * BS_CHUNK;
#pragma unroll
      for (int ni = 0; ni < 8; ++ni) bn[ni] = *(const short8*)(src + ni * 1024);
    }
    short8 a[4];
#pragma unroll
    for (int mi = 0; mi < 4; ++mi)
      a[mi] = *(const short8*)(As + (((mi * 16 + lo) * 1024 + kc * 64 + hi * 16) ^ axor));
    __builtin_amdgcn_s_setprio(1);
#pragma unroll
    for (int ni = 0; ni < 8; ++ni)
#pragma unroll
      for (int mi = 0; mi < 4; ++mi)
        acc[mi][ni] = __builtin_amdgcn_mfma_f32_16x16x32_bf16(a[mi], b[ni], acc[mi][ni], 0, 0, 0);
    __builtin_amdgcn_s_setprio(0);
    if (kc < 15) {
#pragma unroll
      for (int ni = 0; ni < 8; ++ni) b[ni] = bn[ni];
    }
  }

  // -- epilogue: +b2, log_softmax over V, store --
  float b2v[8];
#pragma unroll
  for (int ni = 0; ni < 8; ++ni) b2v[ni] = b2[nbase + ni * 16 + lo];
#pragma unroll
  for (int mi = 0; mi < 4; ++mi)
#pragma unroll
    for (int ni = 0; ni < 8; ++ni)
#pragma unroll
      for (int j = 0; j < 4; ++j) acc[mi][ni][j] += b2v[ni];

  float pm[4][4];
#pragma unroll
  for (int mi = 0; mi < 4; ++mi)
#pragma unroll
    for (int r = 0; r < 4; ++r) {
      float m = -3.402823e38f;
#pragma unroll
      for (int ni = 0; ni < 8; ++ni) m = fmaxf(m, acc[mi][ni][r]);
      pm[mi][r] = m;
    }
#pragma unroll
  for (int off = 1; off < 16; off <<= 1)
#pragma unroll
    for (int mi = 0; mi < 4; ++mi)
#pragma unroll
      for (int r = 0; r < 4; ++r)
        pm[mi][r] = fmaxf(pm[mi][r], __shfl_xor(pm[mi][r], off));
  if (lo == 0) {
#pragma unroll
    for (int mi = 0; mi < 4; ++mi)
#pragma unroll
      for (int r = 0; r < 4; ++r)
        redM[wave * 64 + mi * 16 + hi * 4 + r] = pm[mi][r];
  }
  __syncthreads();
  float rm[4][4];
#pragma unroll
  for (int mi = 0; mi < 4; ++mi)
#pragma unroll
    for (int r = 0; r < 4; ++r) {
      const int row = mi * 16 + hi * 4 + r;
      float m = redM[row];
#pragma unroll
      for (int w = 1; w < 8; ++w) m = fmaxf(m, redM[w * 64 + row]);
      rm[mi][r] = m;
    }

  float ps[4][4];
#pragma unroll
  for (int mi = 0; mi < 4; ++mi)
#pragma unroll
    for (int r = 0; r < 4; ++r) {
      float s = 0.0f;
#pragma unroll
      for (int ni = 0; ni < 8; ++ni) s += __expf(acc[mi][ni][r] - rm[mi][r]);
      ps[mi][r] = s;
    }
#pragma unroll
  for (int off = 1; off < 16; off <<= 1)
#pragma unroll
    for (int mi = 0; mi < 4; ++mi)
#pragma unroll
      for (int r = 0; r < 4; ++r)
        ps[mi][r] += __shfl_xor(ps[mi][r], off);
  if (lo == 0) {
#pragma unroll
    for (int mi = 0; mi < 4; ++mi)
#pragma unroll
      for (int r = 0; r < 4; ++r)
        redS[wave * 64 + mi * 16 + hi * 4 + r] = ps[mi][r];
  }
  __syncthreads();

#pragma unroll
  for (int mi = 0; mi < 4; ++mi)
#pragma unroll
    for (int r = 0; r < 4; ++r) {
      const int row = mi * 16 + hi * 4 + r;
      float s = 0.0f;
#pragma unroll
      for (int w = 0; w < 8; ++w) s += redS[w * 64 + row];
      const float sub = rm[mi][r] + __logf(s);
      float* op = out + (size_t)(m0 + row) * 1024 + nbase + lo;
#pragma unroll
      for (int ni = 0; ni < 8; ++ni) op[ni * 16] = acc[mi][ni][r] - sub;
    }
}

// ---------------------------------------------------------------------------
extern "C" void kernel_launch(void* const* d_in, const int* in_sizes, int n_in,
                              void* d_out, int out_size, void* d_ws, size_t ws_size,
                              hipStream_t stream) {
  const float* enc = (const float*)d_in[0];
  const float* dec = (const float*)d_in[1];
  const float* W1  = (const float*)d_in[2];
  const float* b1  = (const float*)d_in[3];
  const float* W2  = (const float*)d_in[4];
  const float* b2  = (const float*)d_in[5];
  float* out = (float*)d_out;

  char* ws = (char*)d_ws;
  float* ep = (float*)(ws + WS_EP_OFF);
  float* dp = (float*)(ws + WS_DP_OFF);
  char* w2st = ws + WS_W2_OFF;

  prep<<<352, 512, 0, stream>>>(enc, dec, W1, b1, W2, ep, dp, w2st);
  joint<<<1024, 512, SMEM_TOTAL, stream>>>(ep, dp, w2st, b2, out);
}